// Round 2
// baseline (587.814 us; speedup 1.0000x reference)
//
#include <hip/hip_runtime.h>

// EmbeddingBagCollection: F tables [N,D] fp32, jagged sum-pool per bag.
// out[b, f*D + d] = sum_{i in [offs[f][b], offs[f][b+1])} tables[f][values[f][i]][d]
#define F_TABLES 8
#define B_BAGS   8192
#define N_ROWS   200000
#define D_DIM    64
#define T_IDX    163840

// One bag per 16-lane group (4 bags/wave). Each group:
//  - prefetches 16 indices coalesced (1 per lane), broadcasts via shfl
//  - gathers full 256B rows (16 lanes x float4), unroll 8 -> up to 8
//    independent row-gathers in flight per group (32 per wave)
//  - accumulates its own bag directly: no cross-group reduction, direct store.
__global__ __launch_bounds__(256, 8) void ebc_pool_kernel(
    const float* __restrict__ tables,
    const int*   __restrict__ values,
    const int*   __restrict__ offsets,
    float*       __restrict__ out)
{
    const int wave = blockIdx.x * (blockDim.x >> 6) + (threadIdx.x >> 6);
    const int lane = threadIdx.x & 63;
    const int g    = lane >> 4;        // group 0..3 (one bag each)
    const int c    = lane & 15;        // float4 chunk within row

    const int bag = wave * 4 + g;      // 0 .. F*B-1
    const int f   = bag >> 13;         // bag / B_BAGS
    const int b   = bag & (B_BAGS - 1);

    const float4* __restrict__ tab =
        (const float4*)(tables + (size_t)f * N_ROWS * D_DIM);
    const int* __restrict__ vals = values + f * T_IDX;

    const int obase = f * (B_BAGS + 1) + b;
    const int s = offsets[obase];       // 16 lanes same addr -> broadcast
    const int e = offsets[obase + 1];

    float4 acc = make_float4(0.f, 0.f, 0.f, 0.f);

    for (int rb = s; rb < e; rb += 16) {
        const int cnt = min(16, e - rb);          // group-uniform
        int myidx = 0;
        if (c < cnt) myidx = vals[rb + c];        // coalesced 64B idx fetch
        #pragma unroll 8
        for (int j = 0; j < cnt; ++j) {
            const int idx = __shfl(myidx, (g << 4) + j, 64);
            const float4 v = tab[(size_t)idx * (D_DIM / 4) + c];
            acc.x += v.x; acc.y += v.y; acc.z += v.z; acc.w += v.w;
        }
    }

    // group's 16 lanes hold the complete pooled row -> 256B coalesced store
    float4* o = (float4*)(out + (size_t)b * (F_TABLES * D_DIM) + f * D_DIM);
    o[c] = acc;
}

extern "C" void kernel_launch(void* const* d_in, const int* in_sizes, int n_in,
                              void* d_out, int out_size, void* d_ws, size_t ws_size,
                              hipStream_t stream) {
    const float* tables  = (const float*)d_in[0];
    const int*   values  = (const int*)d_in[1];
    const int*   offsets = (const int*)d_in[2];
    float*       out     = (float*)d_out;

    // F*B bags, 4 bags/wave, 4 waves/block -> F*B/16 blocks
    const int blocks = (F_TABLES * B_BAGS) / 16;
    hipLaunchKernelGGL(ebc_pool_kernel, dim3(blocks), dim3(256), 0, stream,
                       tables, values, offsets, out);
}

// Round 3
// 517.848 us; speedup vs baseline: 1.1351x; 1.1351x over previous
//
#include <hip/hip_runtime.h>

// EmbeddingBagCollection: F tables [N,D] fp32, jagged sum-pool per bag.
// out[b, f*D + d] = sum_{i in [offs[f][b], offs[f][b+1])} tables[f][values[f][i]][d]
#define F_TABLES 8
#define B_BAGS   8192
#define N_ROWS   200000
#define D_DIM    64
#define T_IDX    163840

// One wave per bag (wave-uniform loop bounds -> no divergence waste).
// Per 64-index block: one coalesced index prefetch (lane i -> vals[rb+i]),
// then a fully-unrolled 16-step gather; each step is one wave-level
// global_load_dwordx4 covering 4 rows (4 groups x 16 lanes x float4),
// so up to 64 independent row-gathers are in flight per wave.
__global__ __launch_bounds__(256, 8) void ebc_pool_kernel(
    const float* __restrict__ tables,
    const int*   __restrict__ values,
    const int*   __restrict__ offsets,
    float*       __restrict__ out)
{
    const int wave = blockIdx.x * (blockDim.x >> 6) + (threadIdx.x >> 6);
    const int lane = threadIdx.x & 63;
    const int g    = lane >> 4;        // row-group 0..3
    const int c    = lane & 15;        // float4 chunk within row

    const int f = wave >> 13;          // wave / B_BAGS
    const int b = wave & (B_BAGS - 1);

    const float4* __restrict__ tab =
        (const float4*)(tables + (size_t)f * N_ROWS * D_DIM);
    const int* __restrict__ vals = values + f * T_IDX;

    const int obase = f * (B_BAGS + 1) + b;
    const int s = offsets[obase];
    const int e = offsets[obase + 1];

    float4 acc = make_float4(0.f, 0.f, 0.f, 0.f);

    for (int rb = s; rb < e; rb += 64) {
        const int cnt = e - rb;                    // wave-uniform
        int myidx = 0;
        if (lane < cnt) myidx = vals[rb + lane];   // coalesced 256B idx fetch
        #pragma unroll
        for (int jj = 0; jj < 16; ++jj) {
            const int pos = jj * 4 + g;            // group g takes pos%4==g
            const int idx = __shfl(myidx, pos, 64);
            if (pos < cnt) {
                const float4 v = tab[(size_t)idx * (D_DIM / 4) + c];
                acc.x += v.x; acc.y += v.y; acc.z += v.z; acc.w += v.w;
            }
        }
    }

    // fold the 4 group-partials (lanes c, c+16, c+32, c+48 hold same dims)
    #pragma unroll
    for (int m = 16; m < 64; m <<= 1) {
        acc.x += __shfl_xor(acc.x, m, 64);
        acc.y += __shfl_xor(acc.y, m, 64);
        acc.z += __shfl_xor(acc.z, m, 64);
        acc.w += __shfl_xor(acc.w, m, 64);
    }

    if (lane < 16) {
        float4* o = (float4*)(out + (size_t)b * (F_TABLES * D_DIM) + f * D_DIM);
        o[c] = acc;
    }
}

extern "C" void kernel_launch(void* const* d_in, const int* in_sizes, int n_in,
                              void* d_out, int out_size, void* d_ws, size_t ws_size,
                              hipStream_t stream) {
    const float* tables  = (const float*)d_in[0];
    const int*   values  = (const int*)d_in[1];
    const int*   offsets = (const int*)d_in[2];
    float*       out     = (float*)d_out;

    // F*B = 65536 waves, 4 waves per 256-thread block -> 16384 blocks
    const int blocks = (F_TABLES * B_BAGS) / 4;
    hipLaunchKernelGGL(ebc_pool_kernel, dim3(blocks), dim3(256), 0, stream,
                       tables, values, offsets, out);
}